// Round 5
// baseline (185.106 us; speedup 1.0000x reference)
//
#include <hip/hip_runtime.h>
#include <hip/hip_bf16.h>
#include <stdint.h>

// Problem constants (match reference)
#define B_SZ 8
#define T_LEN 1024
#define C_DIM 1024
#define M_ROWS (B_SZ * T_LEN)   // 8192
#define NCH 32
#define CHL (T_LEN / NCH)       // 32

typedef unsigned short ushort_t;
typedef __attribute__((ext_vector_type(8))) short short8;
typedef __attribute__((ext_vector_type(4))) float f32x4;
typedef __attribute__((ext_vector_type(4))) unsigned short us4;

static __device__ __forceinline__ float bf2f(ushort_t u) {
  union { unsigned int i; float f; } x; x.i = ((unsigned int)u) << 16; return x.f;
}
static __device__ __forceinline__ ushort_t f2bf(float f) {
  union { float f; unsigned int i; } x; x.f = f;
  unsigned int r = x.i + 0x7fffu + ((x.i >> 16) & 1u);
  return (ushort_t)(r >> 16);
}

static __device__ __forceinline__ void gload_lds16(const void* g, void* l) {
  __builtin_amdgcn_global_load_lds(
      (const __attribute__((address_space(1))) void*)g,
      (__attribute__((address_space(3))) void*)l, 16, 0, 0);
}

// ---------------- weight f32 -> bf16 conversion (vectorized x4) ------------
__global__ void cvt_w_kernel(const float* __restrict__ wk, const float* __restrict__ wv,
                             const float* __restrict__ wr, const float* __restrict__ wo,
                             ushort_t* __restrict__ out) {
  int gid = blockIdx.x * 256 + threadIdx.x;
  int which = gid >> 18;
  int off = (gid << 2) & ((1 << 20) - 1);
  const float* src = which == 0 ? wk : which == 1 ? wv : which == 2 ? wr : wo;
  float4 v = *(const float4*)(src + off);
  us4 o = {f2bf(v.x), f2bf(v.y), f2bf(v.z), f2bf(v.w)};
  *(us4*)(out + (size_t)gid * 4) = o;
}

// ---------------- time-shift mixing -> bf16 xm (vectorized x4) -------------
__global__ void xm_kernel(const float* __restrict__ x, const float* __restrict__ tm,
                          const float* __restrict__ cm, ushort_t* __restrict__ xmb) {
  int gid = blockIdx.x * 256 + threadIdx.x;
  int c4 = (gid & (C_DIM / 4 - 1)) * 4;
  int t = (gid >> 8) & (T_LEN - 1);
  const float4 zero = {0.f, 0.f, 0.f, 0.f};
  float4 xv = *(const float4*)(x + (size_t)gid * 4);
  float4 xp = (t > 0) ? *(const float4*)(x + (size_t)gid * 4 - C_DIM) : zero;
  float4 xn = (t < T_LEN - 1) ? *(const float4*)(x + (size_t)gid * 4 + C_DIM) : zero;
  float4 tmv = *(const float4*)(tm + c4);
  float4 cmv = *(const float4*)(cm + c4);
  float4 xc = (c4 < C_DIM / 2) ? xp : xn;
  us4 o;
  o.x = f2bf(xv.x * tmv.x + xp.x * (1.f - tmv.x) + xc.x * cmv.x);
  o.y = f2bf(xv.y * tmv.y + xp.y * (1.f - tmv.y) + xc.y * cmv.y);
  o.z = f2bf(xv.z * tmv.z + xp.z * (1.f - tmv.z) + xc.z * cmv.z);
  o.w = f2bf(xv.w * tmv.w + xp.w * (1.f - tmv.w) + xc.w * cmv.w);
  *(us4*)(xmb + (size_t)gid * 4) = o;
}

// ============ fused k/v/r GEMM: 256x256 tile, BK=32, 2-phase ===============
// A = xmb (8192x1024), Bw = [Wk|Wv|Wr] bf16. Grid 384 1-D.
// Mapping: xcd=bid&7 owns 4 contiguous bm-panels (2MB A-slice, L2-fit),
// sweeping jb 0..11: mode=jb>>2 (0:kk exp-clamp->bf16, 1:vv bf16, 2:sr
// sigmoid->bf16), bn=(jb&3)*256.
// 8 waves (2M x 4N), per-wave 128x64 output: 32 MFMA + 12 ds_read per
// vmcnt(0)+barrier drain (2x the 128^2 amortization).
// LDS [256][32] per operand per buf (row stride 64B); slot swizzle:
// physical 8-elt slot = logical ^ ((row>>1)&3), applied as pre-swizzled
// global SOURCE col (linear gload_lds dest) + swizzled ds_read address.
__global__ __launch_bounds__(512, 2) void gemm_fused(const ushort_t* __restrict__ A,
                                                     const ushort_t* __restrict__ Bw,
                                                     ushort_t* __restrict__ outK,
                                                     ushort_t* __restrict__ outV,
                                                     ushort_t* __restrict__ outR) {
  constexpr int K = 1024;
  constexpr int NT = K / 32;
  __shared__ ushort_t As[2][256 * 32];
  __shared__ ushort_t Bs[2][256 * 32];

  const int tid = threadIdx.x;
  const int l = tid & 63;
  const int w = tid >> 6;          // 0..7
  const int wm = w >> 2;           // 0..1
  const int wn = w & 3;            // 0..3
  const int fr = l & 15;
  const int kq = l >> 4;
  const int ps = (kq ^ ((fr >> 1) & 3)) * 8;

  const int bid = blockIdx.x;
  const int xcd = bid & 7;
  const int idx = bid >> 3;        // 0..47
  const int jb = idx >> 2;         // 0..11
  const int bm = (xcd * 4 + (idx & 3)) * 256;
  const int mode = jb >> 2;
  const int bn = (jb & 3) * 256;
  const ushort_t* Bp = Bw + ((size_t)mode << 20);

  f32x4 acc[8][4];
#pragma unroll
  for (int m = 0; m < 8; ++m)
#pragma unroll
    for (int n = 0; n < 4; ++n) acc[m][n] = (f32x4){0.f, 0.f, 0.f, 0.f};

  // staging: per thread 2 A-loads + 2 B-loads (16B each)
  int srow[2], scol[2];
#pragma unroll
  for (int i = 0; i < 2; ++i) {
    int row = w * 32 + i * 16 + (l >> 2);
    srow[i] = row;
    scol[i] = ((l & 3) ^ ((row >> 1) & 3)) * 8;   // pre-swizzled source col
  }
  const ushort_t* AgB = A + (size_t)bm * K;
  const ushort_t* BgB = Bp + (size_t)bn * K;
  const int dst0 = w * 1024 + l * 8;   // elems; lane-stride 16B, wave-uniform base

  auto stage = [&](int buf, int k0) {
#pragma unroll
    for (int i = 0; i < 2; ++i)
      gload_lds16(AgB + (size_t)srow[i] * K + scol[i] + k0, &As[buf][dst0 + i * 512]);
#pragma unroll
    for (int i = 0; i < 2; ++i)
      gload_lds16(BgB + (size_t)srow[i] * K + scol[i] + k0, &Bs[buf][dst0 + i * 512]);
  };

  stage(0, 0);
  asm volatile("s_waitcnt vmcnt(0)" ::: "memory");
  __syncthreads();

  int cur = 0;
  for (int t = 0; t < NT; ++t) {
    if (t < NT - 1) stage(cur ^ 1, (t + 1) * 32);
    short8 af[8], bfr[4];
#pragma unroll
    for (int mf = 0; mf < 8; ++mf)
      af[mf] = *(const short8*)&As[cur][(wm * 128 + mf * 16 + fr) * 32 + ps];
#pragma unroll
    for (int nf = 0; nf < 4; ++nf)
      bfr[nf] = *(const short8*)&Bs[cur][(wn * 64 + nf * 16 + fr) * 32 + ps];
#pragma unroll
    for (int mf = 0; mf < 8; ++mf)
#pragma unroll
      for (int nf = 0; nf < 4; ++nf)
        acc[mf][nf] = __builtin_amdgcn_mfma_f32_16x16x32_bf16(af[mf], bfr[nf], acc[mf][nf], 0, 0, 0);
    asm volatile("s_waitcnt vmcnt(0)" ::: "memory");
    __syncthreads();
    cur ^= 1;
  }

  // C/D layout: col=lane&15, row=(lane>>4)*4+j
#pragma unroll
  for (int mf = 0; mf < 8; ++mf)
#pragma unroll
    for (int nf = 0; nf < 4; ++nf)
#pragma unroll
      for (int j = 0; j < 4; ++j) {
        float v = acc[mf][nf][j];
        size_t ridx = (size_t)(bm + wm * 128 + mf * 16 + kq * 4 + j) * C_DIM +
                      (bn + wn * 64 + nf * 16 + fr);
        if (mode == 0) {
          outK[ridx] = f2bf(__expf(fminf(v, 60.f)));
        } else if (mode == 1) {
          outV[ridx] = f2bf(v);
        } else {
          outR[ridx] = f2bf(1.f / (1.f + __expf(-v)));
        }
      }
}

// ============ output GEMM: 128x128 tile, BK=64, 2-phase ====================
// A = sy (8192x1024), Bw = Wo bf16 -> f32 d_out. Grid 512 1-D, XCD-swizzled.
// 4 waves, per-wave 64x64, 32 MFMA + 16 ds_read per drain (16 K-steps).
// LDS [128][64] (row stride 128B): G4 swizzle, physical 16B-chunk =
// logical ^ (row&7); pre-swizzled global source + swizzled read.
__global__ __launch_bounds__(256, 2) void gemm_out(const ushort_t* __restrict__ A,
                                                   const ushort_t* __restrict__ Bw,
                                                   float* __restrict__ outF) {
  constexpr int K = 1024;
  constexpr int NT = K / 64;
  __shared__ ushort_t As[2][128 * 64];
  __shared__ ushort_t Bs[2][128 * 64];

  const int tid = threadIdx.x;
  const int l = tid & 63;
  const int wave = tid >> 6;
  const int fr = l & 15;
  const int kq = l >> 4;

  const int bid = blockIdx.x;
  const int xcd = bid & 7;
  const int idx = bid >> 3;              // 0..63
  const int jb = idx >> 3;               // 0..7
  const int bm = (xcd * 8 + (idx & 7)) * 128;
  const int bn = jb * 128;

  const int wr = (wave >> 1) * 64;
  const int wc = (wave & 1) * 64;

  f32x4 acc[4][4];
#pragma unroll
  for (int m = 0; m < 4; ++m)
#pragma unroll
    for (int n = 0; n < 4; ++n) acc[m][n] = (f32x4){0.f, 0.f, 0.f, 0.f};

  // staging: per thread 4 A-loads + 4 B-loads
  int srow[4], scol[4];
#pragma unroll
  for (int j = 0; j < 4; ++j) {
    int row = wave * 32 + j * 8 + (l >> 3);
    srow[j] = row;
    scol[j] = ((l & 7) ^ (row & 7)) * 8;
  }
  const ushort_t* AgB = A + (size_t)bm * K;
  const ushort_t* BgB = Bw + (size_t)bn * K;
  const int dst0 = wave * 2048 + l * 8;   // elems

  auto stage = [&](int buf, int k0) {
#pragma unroll
    for (int j = 0; j < 4; ++j)
      gload_lds16(AgB + (size_t)srow[j] * K + scol[j] + k0, &As[buf][dst0 + j * 512]);
#pragma unroll
    for (int j = 0; j < 4; ++j)
      gload_lds16(BgB + (size_t)srow[j] * K + scol[j] + k0, &Bs[buf][dst0 + j * 512]);
  };

  stage(0, 0);
  asm volatile("s_waitcnt vmcnt(0)" ::: "memory");
  __syncthreads();

  const int ps0 = ((0 * 4 + kq) ^ (fr & 7)) * 8;
  const int ps1 = ((1 * 4 + kq) ^ (fr & 7)) * 8;

  int cur = 0;
  for (int t = 0; t < NT; ++t) {
    if (t < NT - 1) stage(cur ^ 1, (t + 1) * 64);
    short8 af[4][2], bfr[4][2];
#pragma unroll
    for (int m = 0; m < 4; ++m) {
      af[m][0] = *(const short8*)&As[cur][(wr + m * 16 + fr) * 64 + ps0];
      af[m][1] = *(const short8*)&As[cur][(wr + m * 16 + fr) * 64 + ps1];
    }
#pragma unroll
    for (int n = 0; n < 4; ++n) {
      bfr[n][0] = *(const short8*)&Bs[cur][(wc + n * 16 + fr) * 64 + ps0];
      bfr[n][1] = *(const short8*)&Bs[cur][(wc + n * 16 + fr) * 64 + ps1];
    }
#pragma unroll
    for (int m = 0; m < 4; ++m)
#pragma unroll
      for (int n = 0; n < 4; ++n)
#pragma unroll
        for (int ks = 0; ks < 2; ++ks)
          acc[m][n] = __builtin_amdgcn_mfma_f32_16x16x32_bf16(af[m][ks], bfr[n][ks], acc[m][n], 0, 0, 0);
    asm volatile("s_waitcnt vmcnt(0)" ::: "memory");
    __syncthreads();
    cur ^= 1;
  }

#pragma unroll
  for (int m = 0; m < 4; ++m)
#pragma unroll
    for (int n = 0; n < 4; ++n)
#pragma unroll
      for (int j = 0; j < 4; ++j)
        outF[(size_t)(bm + wr + m * 16 + kq * 4 + j) * C_DIM + (bn + wc + n * 16 + fr)] =
            acc[m][n][j];
}

// ---------------- wkv chunked scan -----------------------------------------
// Phase A: per (b, chunk, c) compute chunk-local (a, b, p) from zero init.
__global__ void wkv_phaseA(const ushort_t* __restrict__ kk, const ushort_t* __restrict__ vv,
                           const float* __restrict__ td,
                           float* __restrict__ sa, float* __restrict__ sb,
                           float* __restrict__ sp) {
  int gid = blockIdx.x * 256 + threadIdx.x;
  int c = gid & (C_DIM - 1);
  int ch = (gid >> 10) & (NCH - 1);
  int b = gid >> 15;
  float w = td[c] * (1.f / T_LEN);
  size_t base = ((size_t)b * T_LEN + ch * CHL) * C_DIM + c;
  float a = 0.f, bb = 0.f, p = -1e38f;
  for (int t = 0; t < CHL; ++t) {
    float kt = bf2f(kk[base + (size_t)t * C_DIM]);
    float vt = bf2f(vv[base + (size_t)t * C_DIM]);
    float no2 = fmaxf(w + p, kt);
    float e1 = __expf(w + p - no2);
    float e2 = __expf(kt - no2);
    a = e1 * a + e2 * vt;
    bb = e1 * bb + e2;
    p = no2;
  }
  sa[gid] = a; sb[gid] = bb; sp[gid] = p;
}

// Phase C2: inline prefix-combine of chunks < ch (L2-resident state arrays),
// then rerun scan emitting sy = bf16( sigmoid(r) * y ).
__global__ void wkv_phaseC2(const ushort_t* __restrict__ kk, const ushort_t* __restrict__ vv,
                            const ushort_t* __restrict__ sr, const float* __restrict__ td,
                            const float* __restrict__ tf,
                            const float* __restrict__ sa, const float* __restrict__ sb,
                            const float* __restrict__ sp, ushort_t* __restrict__ sy) {
  int gid = blockIdx.x * 256 + threadIdx.x;
  int c = gid & (C_DIM - 1);
  int ch = (gid >> 10) & (NCH - 1);
  int b = gid >> 15;
  float w = td[c] * (1.f / T_LEN);
  float u = tf[c] * (1.f / T_LEN);
  float wL = w * (float)CHL;

  float a = 0.f, bb = 0.f, p = -1e38f;
  size_t sbase = ((size_t)b * NCH) * C_DIM + c;
  for (int j = 0; j < ch; ++j) {
    float ac = sa[sbase + (size_t)j * C_DIM];
    float bc = sb[sbase + (size_t)j * C_DIM];
    float pc = sp[sbase + (size_t)j * C_DIM];
    float pn = fmaxf(p + wL, pc);
    float e1 = __expf(p + wL - pn);
    float e2 = __expf(pc - pn);
    a = e1 * a + e2 * ac;
    bb = e1 * bb + e2 * bc;
    p = pn;
  }

  size_t base = ((size_t)b * T_LEN + ch * CHL) * C_DIM + c;
  for (int t = 0; t < CHL; ++t) {
    float kt = bf2f(kk[base + (size_t)t * C_DIM]);
    float vt = bf2f(vv[base + (size_t)t * C_DIM]);
    float no = fmaxf(p, u + kt);
    float e1 = __expf(p - no);
    float e2 = __expf(u + kt - no);
    float y = (e1 * a + e2 * vt) / (e1 * bb + e2);
    float srv = bf2f(sr[base + (size_t)t * C_DIM]);
    sy[base + (size_t)t * C_DIM] = f2bf(srv * y);
    float no2 = fmaxf(w + p, kt);
    e1 = __expf(w + p - no2);
    e2 = __expf(kt - no2);
    a = e1 * a + e2 * vt;
    bb = e1 * bb + e2;
    p = no2;
  }
}

// ---------------------------------------------------------------------------
extern "C" void kernel_launch(void* const* d_in, const int* in_sizes, int n_in,
                              void* d_out, int out_size, void* d_ws, size_t ws_size,
                              hipStream_t stream) {
  const float* x  = (const float*)d_in[0];
  const float* td = (const float*)d_in[1];
  const float* tf = (const float*)d_in[2];
  const float* tm = (const float*)d_in[3];
  const float* cm = (const float*)d_in[4];
  const float* Wk = (const float*)d_in[5];
  const float* Wv = (const float*)d_in[6];
  const float* Wr = (const float*)d_in[7];
  const float* Wo = (const float*)d_in[8];

  const size_t MC = (size_t)M_ROWS * C_DIM;
  const size_t CC = (size_t)C_DIM * C_DIM;

  char* ws = (char*)d_ws;
  ushort_t* xmb = (ushort_t*)ws; ws += MC * 2;
  ushort_t* Wb  = (ushort_t*)ws; ws += 4 * CC * 2;
  ushort_t* kk  = (ushort_t*)ws; ws += MC * 2;
  ushort_t* vv  = (ushort_t*)ws; ws += MC * 2;
  ushort_t* sr  = (ushort_t*)ws; ws += MC * 2;
  ushort_t* sy  = (ushort_t*)ws; ws += MC * 2;
  float* sa = (float*)ws; ws += (size_t)B_SZ * NCH * C_DIM * 4;
  float* sb = (float*)ws; ws += (size_t)B_SZ * NCH * C_DIM * 4;
  float* sp = (float*)ws; ws += (size_t)B_SZ * NCH * C_DIM * 4;

  cvt_w_kernel<<<(4 * CC / 4) / 256, 256, 0, stream>>>(Wk, Wv, Wr, Wo, Wb);
  xm_kernel<<<(MC / 4) / 256, 256, 0, stream>>>(x, tm, cm, xmb);

  // fused k/v/r projections: 256^2 tiles, 384 blocks, XCD-swizzled
  gemm_fused<<<dim3(384), 512, 0, stream>>>(xmb, Wb, kk, vv, sr);

  wkv_phaseA<<<(B_SZ * NCH * C_DIM) / 256, 256, 0, stream>>>(kk, vv, td, sa, sb, sp);
  wkv_phaseC2<<<(B_SZ * NCH * C_DIM) / 256, 256, 0, stream>>>(kk, vv, sr, td, tf, sa, sb, sp, sy);

  // output projection: 128x128 BK=64, 512 blocks, XCD-swizzled
  gemm_out<<<dim3(512), 256, 0, stream>>>(sy, Wb + 3 * CC, (float*)d_out);
}

// Round 6
// 153.881 us; speedup vs baseline: 1.2029x; 1.2029x over previous
//
#include <hip/hip_runtime.h>
#include <hip/hip_bf16.h>
#include <stdint.h>

// Problem constants (match reference)
#define B_SZ 8
#define T_LEN 1024
#define C_DIM 1024
#define M_ROWS (B_SZ * T_LEN)   // 8192
#define NCH 32
#define CHL (T_LEN / NCH)       // 32

typedef unsigned short ushort_t;
typedef __attribute__((ext_vector_type(8))) short short8;
typedef __attribute__((ext_vector_type(4))) float f32x4;
typedef __attribute__((ext_vector_type(4))) unsigned short us4;

static __device__ __forceinline__ float bf2f(ushort_t u) {
  union { unsigned int i; float f; } x; x.i = ((unsigned int)u) << 16; return x.f;
}
static __device__ __forceinline__ ushort_t f2bf(float f) {
  union { float f; unsigned int i; } x; x.f = f;
  unsigned int r = x.i + 0x7fffu + ((x.i >> 16) & 1u);
  return (ushort_t)(r >> 16);
}

static __device__ __forceinline__ void gload_lds16(const void* g, void* l) {
  __builtin_amdgcn_global_load_lds(
      (const __attribute__((address_space(1))) void*)g,
      (__attribute__((address_space(3))) void*)l, 16, 0, 0);
}

// ---------------- weight f32 -> bf16 conversion (vectorized x4) ------------
__global__ void cvt_w_kernel(const float* __restrict__ wk, const float* __restrict__ wv,
                             const float* __restrict__ wr, const float* __restrict__ wo,
                             ushort_t* __restrict__ out) {
  int gid = blockIdx.x * 256 + threadIdx.x;
  int which = gid >> 18;
  int off = (gid << 2) & ((1 << 20) - 1);
  const float* src = which == 0 ? wk : which == 1 ? wv : which == 2 ? wr : wo;
  float4 v = *(const float4*)(src + off);
  us4 o = {f2bf(v.x), f2bf(v.y), f2bf(v.z), f2bf(v.w)};
  *(us4*)(out + (size_t)gid * 4) = o;
}

// ---------------- time-shift mixing -> bf16 xm (vectorized x4) -------------
__global__ void xm_kernel(const float* __restrict__ x, const float* __restrict__ tm,
                          const float* __restrict__ cm, ushort_t* __restrict__ xmb) {
  int gid = blockIdx.x * 256 + threadIdx.x;
  int c4 = (gid & (C_DIM / 4 - 1)) * 4;
  int t = (gid >> 8) & (T_LEN - 1);
  const float4 zero = {0.f, 0.f, 0.f, 0.f};
  float4 xv = *(const float4*)(x + (size_t)gid * 4);
  float4 xp = (t > 0) ? *(const float4*)(x + (size_t)gid * 4 - C_DIM) : zero;
  float4 xn = (t < T_LEN - 1) ? *(const float4*)(x + (size_t)gid * 4 + C_DIM) : zero;
  float4 tmv = *(const float4*)(tm + c4);
  float4 cmv = *(const float4*)(cm + c4);
  float4 xc = (c4 < C_DIM / 2) ? xp : xn;
  us4 o;
  o.x = f2bf(xv.x * tmv.x + xp.x * (1.f - tmv.x) + xc.x * cmv.x);
  o.y = f2bf(xv.y * tmv.y + xp.y * (1.f - tmv.y) + xc.y * cmv.y);
  o.z = f2bf(xv.z * tmv.z + xp.z * (1.f - tmv.z) + xc.z * cmv.z);
  o.w = f2bf(xv.w * tmv.w + xp.w * (1.f - tmv.w) + xc.w * cmv.w);
  *(us4*)(xmb + (size_t)gid * 4) = o;
}

// ============ fused k/v/r GEMM: 128x128, BK=32, TRIPLE-buf counted vmcnt ====
// A = xmb (8192x1024), Bw = [Wk|Wv|Wr] bf16. Grid 1536 1-D (6/CU, 2 even
// rounds at 3 blocks/CU; LDS 48 KB).
// Pipeline: stage(t+2) issued at iter t -> full iteration of latency slack;
// vmcnt(4) (one 4-load stage in flight) + raw s_barrier (no implicit full
// drain). Hazards: WAR ordered by end-of-(t-1) barrier (ds_reads drain via
// lgkmcnt before their MFMAs); RAW by end-of-(t-1) vmcnt(4).
// XCD swizzle: xcd=bid&7 owns 8 contiguous bm-panels (2MB A-slice, L2-fit).
// LDS slot swizzle (measured 0-conflict): physical 8-elt slot =
// logical ^ ((row>>1)&3); pre-swizzled global SOURCE col + swizzled read.
__global__ __launch_bounds__(256, 3) void gemm_fused(const ushort_t* __restrict__ A,
                                                     const ushort_t* __restrict__ Bw,
                                                     ushort_t* __restrict__ outK,
                                                     ushort_t* __restrict__ outV,
                                                     ushort_t* __restrict__ outR) {
  constexpr int K = 1024;
  constexpr int NT = K / 32;           // 32 K-steps
  __shared__ ushort_t As[3][128 * 32];
  __shared__ ushort_t Bs[3][128 * 32];

  const int tid = threadIdx.x;
  const int lane = tid & 63;
  const int wave = tid >> 6;

  const int bid = blockIdx.x;
  const int xcd = bid & 7;
  const int r = bid >> 3;
  const int bm = (xcd * 8 + (r & 7)) * 128;
  const int jb = r >> 3;                     // 0..23
  const int mode = jb >> 3;                  // 0:k 1:v 2:r
  const int bn = (jb & 7) * 128;
  const ushort_t* Bp = Bw + ((size_t)mode << 20);

  const int wr = (wave >> 1) * 64;
  const int wc = (wave & 1) * 64;

  f32x4 acc[4][4];
#pragma unroll
  for (int m = 0; m < 4; ++m)
#pragma unroll
    for (int n = 0; n < 4; ++n) acc[m][n] = (f32x4){0.f, 0.f, 0.f, 0.f};

  // staging addressing (pre-swizzled global source column)
  const int srow = tid >> 2;                         // 0..63
  const int scol = (((tid & 3) ^ ((srow >> 1) & 3)) * 8);
  const ushort_t* Ag = A + (size_t)(bm + srow) * K + scol;
  const ushort_t* Bg = Bp + (size_t)(bn + srow) * K + scol;

  // read addressing: physical slot = kq ^ ((row>>1)&3) == kq ^ ((fr>>1)&3)
  const int fr = lane & 15;
  const int kq = lane >> 4;
  const int ps = (kq ^ ((fr >> 1) & 3)) * 8;

  auto stage = [&](int buf, int k0) {
    ushort_t* ap = &As[buf][tid * 8];
    ushort_t* bp = &Bs[buf][tid * 8];
    gload_lds16(Ag + k0, ap);
    gload_lds16(Ag + (size_t)64 * K + k0, ap + 64 * 32);
    gload_lds16(Bg + k0, bp);
    gload_lds16(Bg + (size_t)64 * K + k0, bp + 64 * 32);
  };

  // prologue: buf0, buf1 in flight; wait only for buf0 (vmcnt(4))
  stage(0, 0);
  stage(1, 32);
  asm volatile("s_waitcnt vmcnt(4)" ::: "memory");
  __builtin_amdgcn_s_barrier();
  __builtin_amdgcn_sched_barrier(0);

  int cur = 0, nxt2 = 2;
#pragma unroll 1
  for (int t = 0; t < NT; ++t) {
    if (t + 2 < NT) stage(nxt2, (t + 2) * 32);
    const ushort_t* asb = &As[cur][0];
    const ushort_t* bsb = &Bs[cur][0];
    short8 af[4], bfr[4];
#pragma unroll
    for (int m = 0; m < 4; ++m)
      af[m] = *(const short8*)&asb[(wr + m * 16 + fr) * 32 + ps];
#pragma unroll
    for (int n = 0; n < 4; ++n)
      bfr[n] = *(const short8*)&bsb[(wc + n * 16 + fr) * 32 + ps];
#pragma unroll
    for (int m = 0; m < 4; ++m)
#pragma unroll
      for (int n = 0; n < 4; ++n)
        acc[m][n] = __builtin_amdgcn_mfma_f32_16x16x32_bf16(af[m], bfr[n], acc[m][n], 0, 0, 0);
    if (t + 2 < NT) {
      asm volatile("s_waitcnt vmcnt(4)" ::: "memory");
    } else {
      asm volatile("s_waitcnt vmcnt(0)" ::: "memory");
    }
    __builtin_amdgcn_s_barrier();
    __builtin_amdgcn_sched_barrier(0);
    cur = (cur == 2) ? 0 : cur + 1;
    nxt2 = (nxt2 == 2) ? 0 : nxt2 + 1;
  }

  // C/D layout: col=lane&15, row=(lane>>4)*4+j
#pragma unroll
  for (int m = 0; m < 4; ++m)
#pragma unroll
    for (int n = 0; n < 4; ++n)
#pragma unroll
      for (int j = 0; j < 4; ++j) {
        float v = acc[m][n][j];
        size_t idx = (size_t)(bm + wr + m * 16 + kq * 4 + j) * C_DIM + (bn + wc + n * 16 + fr);
        if (mode == 0) {
          outK[idx] = f2bf(__expf(fminf(v, 60.f)));
        } else if (mode == 1) {
          outV[idx] = f2bf(v);
        } else {
          outR[idx] = f2bf(1.f / (1.f + __expf(-v)));
        }
      }
}

// ============ output GEMM: 128x128 tile, BK=64, 2-phase (R5, kept) =========
__global__ __launch_bounds__(256, 2) void gemm_out(const ushort_t* __restrict__ A,
                                                   const ushort_t* __restrict__ Bw,
                                                   float* __restrict__ outF) {
  constexpr int K = 1024;
  constexpr int NT = K / 64;
  __shared__ ushort_t As[2][128 * 64];
  __shared__ ushort_t Bs[2][128 * 64];

  const int tid = threadIdx.x;
  const int l = tid & 63;
  const int wave = tid >> 6;
  const int fr = l & 15;
  const int kq = l >> 4;

  const int bid = blockIdx.x;
  const int xcd = bid & 7;
  const int idx = bid >> 3;              // 0..63
  const int jb = idx >> 3;               // 0..7
  const int bm = (xcd * 8 + (idx & 7)) * 128;
  const int bn = jb * 128;

  const int wr = (wave >> 1) * 64;
  const int wc = (wave & 1) * 64;

  f32x4 acc[4][4];
#pragma unroll
  for (int m = 0; m < 4; ++m)
#pragma unroll
    for (int n = 0; n < 4; ++n) acc[m][n] = (f32x4){0.f, 0.f, 0.f, 0.f};

  int srow[4], scol[4];
#pragma unroll
  for (int j = 0; j < 4; ++j) {
    int row = wave * 32 + j * 8 + (l >> 3);
    srow[j] = row;
    scol[j] = ((l & 7) ^ (row & 7)) * 8;
  }
  const ushort_t* AgB = A + (size_t)bm * K;
  const ushort_t* BgB = Bw + (size_t)bn * K;
  const int dst0 = wave * 2048 + l * 8;

  auto stage = [&](int buf, int k0) {
#pragma unroll
    for (int j = 0; j < 4; ++j)
      gload_lds16(AgB + (size_t)srow[j] * K + scol[j] + k0, &As[buf][dst0 + j * 512]);
#pragma unroll
    for (int j = 0; j < 4; ++j)
      gload_lds16(BgB + (size_t)srow[j] * K + scol[j] + k0, &Bs[buf][dst0 + j * 512]);
  };

  stage(0, 0);
  asm volatile("s_waitcnt vmcnt(0)" ::: "memory");
  __syncthreads();

  const int ps0 = ((0 * 4 + kq) ^ (fr & 7)) * 8;
  const int ps1 = ((1 * 4 + kq) ^ (fr & 7)) * 8;

  int cur = 0;
  for (int t = 0; t < NT; ++t) {
    if (t < NT - 1) stage(cur ^ 1, (t + 1) * 64);
    short8 af[4][2], bfr[4][2];
#pragma unroll
    for (int m = 0; m < 4; ++m) {
      af[m][0] = *(const short8*)&As[cur][(wr + m * 16 + fr) * 64 + ps0];
      af[m][1] = *(const short8*)&As[cur][(wr + m * 16 + fr) * 64 + ps1];
    }
#pragma unroll
    for (int n = 0; n < 4; ++n) {
      bfr[n][0] = *(const short8*)&Bs[cur][(wc + n * 16 + fr) * 64 + ps0];
      bfr[n][1] = *(const short8*)&Bs[cur][(wc + n * 16 + fr) * 64 + ps1];
    }
#pragma unroll
    for (int m = 0; m < 4; ++m)
#pragma unroll
      for (int n = 0; n < 4; ++n)
#pragma unroll
        for (int ks = 0; ks < 2; ++ks)
          acc[m][n] = __builtin_amdgcn_mfma_f32_16x16x32_bf16(af[m][ks], bfr[n][ks], acc[m][n], 0, 0, 0);
    asm volatile("s_waitcnt vmcnt(0)" ::: "memory");
    __syncthreads();
    cur ^= 1;
  }

#pragma unroll
  for (int m = 0; m < 4; ++m)
#pragma unroll
    for (int n = 0; n < 4; ++n)
#pragma unroll
      for (int j = 0; j < 4; ++j)
        outF[(size_t)(bm + wr + m * 16 + kq * 4 + j) * C_DIM + (bn + wc + n * 16 + fr)] =
            acc[m][n][j];
}

// ---------------- wkv chunked scan -----------------------------------------
__global__ void wkv_phaseA(const ushort_t* __restrict__ kk, const ushort_t* __restrict__ vv,
                           const float* __restrict__ td,
                           float* __restrict__ sa, float* __restrict__ sb,
                           float* __restrict__ sp) {
  int gid = blockIdx.x * 256 + threadIdx.x;
  int c = gid & (C_DIM - 1);
  int ch = (gid >> 10) & (NCH - 1);
  int b = gid >> 15;
  float w = td[c] * (1.f / T_LEN);
  size_t base = ((size_t)b * T_LEN + ch * CHL) * C_DIM + c;
  float a = 0.f, bb = 0.f, p = -1e38f;
  for (int t = 0; t < CHL; ++t) {
    float kt = bf2f(kk[base + (size_t)t * C_DIM]);
    float vt = bf2f(vv[base + (size_t)t * C_DIM]);
    float no2 = fmaxf(w + p, kt);
    float e1 = __expf(w + p - no2);
    float e2 = __expf(kt - no2);
    a = e1 * a + e2 * vt;
    bb = e1 * bb + e2;
    p = no2;
  }
  sa[gid] = a; sb[gid] = bb; sp[gid] = p;
}

__global__ void wkv_phaseC2(const ushort_t* __restrict__ kk, const ushort_t* __restrict__ vv,
                            const ushort_t* __restrict__ sr, const float* __restrict__ td,
                            const float* __restrict__ tf,
                            const float* __restrict__ sa, const float* __restrict__ sb,
                            const float* __restrict__ sp, ushort_t* __restrict__ sy) {
  int gid = blockIdx.x * 256 + threadIdx.x;
  int c = gid & (C_DIM - 1);
  int ch = (gid >> 10) & (NCH - 1);
  int b = gid >> 15;
  float w = td[c] * (1.f / T_LEN);
  float u = tf[c] * (1.f / T_LEN);
  float wL = w * (float)CHL;

  float a = 0.f, bb = 0.f, p = -1e38f;
  size_t sbase = ((size_t)b * NCH) * C_DIM + c;
  for (int j = 0; j < ch; ++j) {
    float ac = sa[sbase + (size_t)j * C_DIM];
    float bc = sb[sbase + (size_t)j * C_DIM];
    float pc = sp[sbase + (size_t)j * C_DIM];
    float pn = fmaxf(p + wL, pc);
    float e1 = __expf(p + wL - pn);
    float e2 = __expf(pc - pn);
    a = e1 * a + e2 * ac;
    bb = e1 * bb + e2 * bc;
    p = pn;
  }

  size_t base = ((size_t)b * T_LEN + ch * CHL) * C_DIM + c;
  for (int t = 0; t < CHL; ++t) {
    float kt = bf2f(kk[base + (size_t)t * C_DIM]);
    float vt = bf2f(vv[base + (size_t)t * C_DIM]);
    float no = fmaxf(p, u + kt);
    float e1 = __expf(p - no);
    float e2 = __expf(u + kt - no);
    float y = (e1 * a + e2 * vt) / (e1 * bb + e2);
    float srv = bf2f(sr[base + (size_t)t * C_DIM]);
    sy[base + (size_t)t * C_DIM] = f2bf(srv * y);
    float no2 = fmaxf(w + p, kt);
    e1 = __expf(w + p - no2);
    e2 = __expf(kt - no2);
    a = e1 * a + e2 * vt;
    bb = e1 * bb + e2;
    p = no2;
  }
}

// ---------------------------------------------------------------------------
extern "C" void kernel_launch(void* const* d_in, const int* in_sizes, int n_in,
                              void* d_out, int out_size, void* d_ws, size_t ws_size,
                              hipStream_t stream) {
  const float* x  = (const float*)d_in[0];
  const float* td = (const float*)d_in[1];
  const float* tf = (const float*)d_in[2];
  const float* tm = (const float*)d_in[3];
  const float* cm = (const float*)d_in[4];
  const float* Wk = (const float*)d_in[5];
  const float* Wv = (const float*)d_in[6];
  const float* Wr = (const float*)d_in[7];
  const float* Wo = (const float*)d_in[8];

  const size_t MC = (size_t)M_ROWS * C_DIM;
  const size_t CC = (size_t)C_DIM * C_DIM;

  char* ws = (char*)d_ws;
  ushort_t* xmb = (ushort_t*)ws; ws += MC * 2;
  ushort_t* Wb  = (ushort_t*)ws; ws += 4 * CC * 2;
  ushort_t* kk  = (ushort_t*)ws; ws += MC * 2;
  ushort_t* vv  = (ushort_t*)ws; ws += MC * 2;
  ushort_t* sr  = (ushort_t*)ws; ws += MC * 2;
  ushort_t* sy  = (ushort_t*)ws; ws += MC * 2;
  float* sa = (float*)ws; ws += (size_t)B_SZ * NCH * C_DIM * 4;
  float* sb = (float*)ws; ws += (size_t)B_SZ * NCH * C_DIM * 4;
  float* sp = (float*)ws; ws += (size_t)B_SZ * NCH * C_DIM * 4;

  cvt_w_kernel<<<(4 * CC / 4) / 256, 256, 0, stream>>>(Wk, Wv, Wr, Wo, Wb);
  xm_kernel<<<(MC / 4) / 256, 256, 0, stream>>>(x, tm, cm, xmb);

  // fused k/v/r projections: 128^2 tiles, 1536 blocks, triple-buf counted
  gemm_fused<<<dim3(1536), 256, 0, stream>>>(xmb, Wb, kk, vv, sr);

  wkv_phaseA<<<(B_SZ * NCH * C_DIM) / 256, 256, 0, stream>>>(kk, vv, td, sa, sb, sp);
  wkv_phaseC2<<<(B_SZ * NCH * C_DIM) / 256, 256, 0, stream>>>(kk, vv, sr, td, tf, sa, sb, sp, sy);

  // output projection: 128x128 BK=64, 512 blocks, XCD-swizzled
  gemm_out<<<dim3(512), 256, 0, stream>>>(sy, Wb + 3 * CC, (float*)d_out);
}